// Round 15
// baseline (449.104 us; speedup 1.0000x reference)
//
#include <hip/hip_runtime.h>

#define K_CB 1024
#define D_EMB 256
#define DECAY_F 0.900009f
#define OMD_F 0.099991f
#define EPS_VQ 1e-5f
#define MAX_FLAG 65536
#define GAP_TAU 3e-4f
#define RB 16                    // flagged rows per refine block

typedef __bf16 bf16x8 __attribute__((ext_vector_type(8)));
typedef float f32x4 __attribute__((ext_vector_type(4)));

__device__ __forceinline__ unsigned short bf16rn(float f) {
  unsigned u = __float_as_uint(f);
  return (unsigned short)((u + 0x7fffu + ((u >> 16) & 1u)) >> 16);
}

#define STAGE16(srcp, dstp)                                                        \
  __builtin_amdgcn_global_load_lds(                                               \
      (const __attribute__((address_space(1))) unsigned int*)(srcp),              \
      (__attribute__((address_space(3))) unsigned int*)(dstp), 16, 0, 0)

#define VW4  asm volatile("s_waitcnt vmcnt(4)" ::: "memory")
#define VW0  asm volatile("s_waitcnt vmcnt(0)" ::: "memory")
#define SBAR __builtin_amdgcn_s_barrier()
#define SCHED0 __builtin_amdgcn_sched_barrier(0)

// ---------------- fp32 -> bf16 (hi only) ----------------
__global__ __launch_bounds__(256) void vq_split_hi(const float* __restrict__ src,
                                                   unsigned short* __restrict__ dst,
                                                   int nrows) {
  int g = blockIdx.x * 256 + threadIdx.x;
  int row = g >> 6, d0 = (g & 63) << 2;
  if (row >= nrows) return;
  float4 v = *(const float4*)(src + (size_t)row * D_EMB + d0);
  ushort4 hi;
  hi.x = bf16rn(v.x); hi.y = bf16rn(v.y); hi.z = bf16rn(v.z); hi.w = bf16rn(v.w);
  *(ushort4*)(dst + (size_t)row * D_EMB + d0) = hi;
}

// ---------------- w transpose: wT[d][k] = w[k][d] ----------------
__global__ __launch_bounds__(256) void vq_transpose(const float* __restrict__ w,
                                                    float* __restrict__ wT) {
  __shared__ float tile[64][65];
  int bk = (blockIdx.x & 15) * 64;
  int bd = (blockIdx.x >> 4) * 64;
  for (int i = threadIdx.x; i < 64 * 16; i += 256) {
    int kk = i >> 4, dd4 = (i & 15) * 4;
    float4 v = *(const float4*)(w + (size_t)(bk + kk) * D_EMB + bd + dd4);
    tile[kk][dd4]     = v.x; tile[kk][dd4 + 1] = v.y;
    tile[kk][dd4 + 2] = v.z; tile[kk][dd4 + 3] = v.w;
  }
  __syncthreads();
  for (int i = threadIdx.x; i < 64 * 64; i += 256) {
    int dd = i >> 6, kk = i & 63;
    wT[(size_t)(bd + dd) * K_CB + bk + kk] = tile[kk][dd];
  }
}

// ===== numpy float32 pairwise sum-of-squares emulation (exact) =====
__device__ __forceinline__ float np_block128_sq(const float* p) {
  float r[8];
#pragma unroll
  for (int j = 0; j < 8; ++j) r[j] = __fmul_rn(p[j], p[j]);
  for (int i = 8; i < 128; i += 8) {
#pragma unroll
    for (int j = 0; j < 8; ++j)
      r[j] = __fadd_rn(r[j], __fmul_rn(p[i + j], p[i + j]));
  }
  return __fadd_rn(__fadd_rn(__fadd_rn(r[0], r[1]), __fadd_rn(r[2], r[3])),
                   __fadd_rn(__fadd_rn(r[4], r[5]), __fadd_rn(r[6], r[7])));
}
__device__ __forceinline__ float np_sumsq_256(const float* p) {
  return __fadd_rn(np_block128_sq(p), np_block128_sq(p + 128));
}

__global__ __launch_bounds__(256) void vq_wsq_np(const float* __restrict__ w,
                                                 float* __restrict__ Cnp) {
  int k = blockIdx.x * 256 + threadIdx.x;
  if (k < K_CB) Cnp[k] = np_sumsq_256(w + (size_t)k * D_EMB);
}

// ---------------- MFMA screening GEMM, v7: A-in-registers, B-only staging ----------------
// K=256 bf16-hi screen. Per wave: its 64 rows of x2 live in 32 bf16x8 VGPRs for the
// whole kernel (loaded once). LDS: B double-buffer 2x16KB + Cnp mirror 4KB. Per stage:
// vmcnt(4) -> s_barrier -> 8 B ds_reads + 32 MFMA -> s_barrier -> stage(it+2).
__global__ __launch_bounds__(256, 2) void vq_gemm(
    const unsigned short* __restrict__ x2, const unsigned short* __restrict__ w2,
    const float* __restrict__ Cnp, int* __restrict__ indices,
    int* __restrict__ flagged, int* __restrict__ flag_count) {
  __shared__ unsigned short tB[2][128 * 64];   // 32KB
  __shared__ float CnpS[K_CB];                 // 4KB (also merge scratch at end)
  const int t = threadIdx.x;
  const int wid = t >> 6;
  const int wr = wid >> 1, wc = wid & 1;       // 2x2 wave grid, each 64(rows)x64(cols)
  const int lane = t & 63;
  const int q = lane >> 4, c = lane & 15;
  const int h = c & 7;
  const int mb = blockIdx.x * 128;

  // ---- one-time staging: Cnp -> LDS (keeps fold reads out of the vmcnt domain)
  STAGE16(Cnp + t * 4, &CnpS[t * 4]);

  // ---- one-time A load: 64 rows x K=256 per wave -> 32 bf16x8 (128 VGPR)
  bf16x8 aR[4][8];
  {
    const unsigned short* aP = x2 + (size_t)(mb + wr * 64 + c) * D_EMB + q * 8;
#pragma unroll
    for (int m = 0; m < 4; ++m)
#pragma unroll
      for (int ks = 0; ks < 8; ++ks)
        aR[m][ks] = *(const bf16x8*)(aP + m * 16 * D_EMB + ks * 32);
  }

  // ---- per-thread B staging base (pre-swizzled source slot)
  const int srow = t >> 3;                     // 0..31
  const int ssl  = (t & 7) ^ (srow & 7);
  const unsigned short* bP = w2 + (size_t)srow * D_EMB + ssl * 8;

#define STAGE_B(ntv, kcv, bufb)                                               \
  do {                                                                        \
    _Pragma("unroll")                                                         \
    for (int cix = 0; cix < 4; ++cix) {                                       \
      STAGE16(bP + cix * (32 * D_EMB) + (ntv) * (128 * D_EMB) + (kcv) * 64,   \
              &tB[bufb][(cix * 256 + t) * 8]);                                \
    }                                                                         \
  } while (0)

  float b1[4][4], b2v[4][4];
  unsigned bip[4][2];                          // bi packed 2x16b per (m, j-pair)
#pragma unroll
  for (int m = 0; m < 4; ++m) {
#pragma unroll
    for (int j = 0; j < 4; ++j) { b1[m][j] = 3.4e38f; b2v[m][j] = 3.4e38f; }
    bip[m][0] = 0; bip[m][1] = 0;
  }

  // prologue: stages (0,0)->buf0, (0,1)->buf1  (8 B-loads in flight)
  STAGE_B(0, 0, 0);
  STAGE_B(0, 1, 1);

  for (int nt = 0; nt < 8; ++nt) {
    f32x4 acc[4][4];
#pragma unroll
    for (int m = 0; m < 4; ++m)
#pragma unroll
      for (int n = 0; n < 4; ++n) acc[m][n] = (f32x4){0.f, 0.f, 0.f, 0.f};

#pragma unroll
    for (int kc = 0; kc < 4; ++kc) {
      const int buf = kc & 1;                  // it = nt*4+kc; parity == kc&1
      if (nt == 7 && kc == 3) { VW0; } else { VW4; }   // drain THIS stage only
      SBAR;                                    // all waves' stage data visible
      SCHED0;
      const unsigned short* tBc = tB[buf];
#pragma unroll
      for (int n = 0; n < 4; ++n) {
        int rb = (wc * 64 + n * 16 + c) * 64;
        bf16x8 bf0 = *(const bf16x8*)&tBc[rb + ((q) ^ h) * 8];
        bf16x8 bf1 = *(const bf16x8*)&tBc[rb + ((4 + q) ^ h) * 8];
#pragma unroll
        for (int m = 0; m < 4; ++m) {
          acc[m][n] = __builtin_amdgcn_mfma_f32_16x16x32_bf16(aR[m][kc * 2],     bf0, acc[m][n], 0, 0, 0);
          acc[m][n] = __builtin_amdgcn_mfma_f32_16x16x32_bf16(aR[m][kc * 2 + 1], bf1, acc[m][n], 0, 0, 0);
        }
      }
      SBAR;                                    // WAR: all waves done reading buf
      // restage it+2 into the buffer just freed (stays in flight across barriers)
      if (kc < 2) {
        STAGE_B(nt, kc + 2, buf);
      } else if (nt < 7) {
        STAGE_B(nt + 1, kc - 2, buf);
      }
    }

    // fold this 128-codeword tile (cn via LDS -> lgkm domain, vmcnt untouched)
    const int nbase = nt << 7;
#pragma unroll
    for (int n = 0; n < 4; ++n) {
      int   ckn = nbase + wc * 64 + n * 16 + c;
      float cn  = CnpS[ckn];
#pragma unroll
      for (int m = 0; m < 4; ++m)
#pragma unroll
        for (int j = 0; j < 4; ++j) {
          float d = __fmaf_rn(-2.0f, acc[m][n][j], cn);
          if (d < b1[m][j]) {
            b2v[m][j] = b1[m][j]; b1[m][j] = d;
            int sh = (j & 1) * 16;
            bip[m][j >> 1] = (bip[m][j >> 1] & ~(0xFFFFu << sh)) | ((unsigned)ckn << sh);
          } else if (d < b2v[m][j]) {
            b2v[m][j] = d;
          }
        }
    }
  }

  // unpack bi + final butterfly over the 16 c-lanes per (m,j)
  int bi[4][4];
#pragma unroll
  for (int m = 0; m < 4; ++m)
#pragma unroll
    for (int j = 0; j < 4; ++j)
      bi[m][j] = (int)((bip[m][j >> 1] >> ((j & 1) * 16)) & 0xFFFFu);

#pragma unroll
  for (int m = 0; m < 4; ++m)
#pragma unroll
    for (int j = 0; j < 4; ++j) {
      float db = b1[m][j], db2 = b2v[m][j];
      int   di = bi[m][j];
#pragma unroll
      for (int off = 1; off < 16; off <<= 1) {
        float ob  = __shfl_xor(db, off, 64);
        float ob2 = __shfl_xor(db2, off, 64);
        int   oi  = __shfl_xor(di, off, 64);
        float lo = fminf(db, ob), hi2 = fmaxf(db, ob);
        db2 = fminf(fminf(db2, ob2), hi2);
        di  = (ob < db || (ob == db && oi < di)) ? oi : di;
        db  = lo;
      }
      b1[m][j] = db; b2v[m][j] = db2; bi[m][j] = di;
    }

  // ---- cross-wave merge: each row is covered by waves (wr,0) and (wr,1) ----
  float* sB1 = CnpS;                           // reuse (Cnp reads all done)
  float* sB2 = sB1 + 128;
  int*   sBI = (int*)(sB2 + 128);
  __syncthreads();
  if (wc == 1 && c == 0) {
#pragma unroll
    for (int m = 0; m < 4; ++m)
#pragma unroll
      for (int j = 0; j < 4; ++j) {
        int r = wr * 64 + m * 16 + q * 4 + j;
        sB1[r] = b1[m][j]; sB2[r] = b2v[m][j]; sBI[r] = bi[m][j];
      }
  }
  __syncthreads();
  if (wc == 0 && c == 0) {
#pragma unroll
    for (int m = 0; m < 4; ++m)
#pragma unroll
      for (int j = 0; j < 4; ++j) {
        int r = wr * 64 + m * 16 + q * 4 + j;
        float o1 = sB1[r], o2 = sB2[r];
        int   oi = sBI[r];
        float best, sec; int bidx;
        if (o1 < b1[m][j] || (o1 == b1[m][j] && oi < bi[m][j])) {
          best = o1; bidx = oi; sec = fminf(o2, b1[m][j]);
        } else {
          best = b1[m][j]; bidx = bi[m][j]; sec = fminf(b2v[m][j], o1);
        }
        indices[mb + r] = bidx;
        if (sec - best < GAP_TAU) {
          int p = atomicAdd(flag_count, 1);
          if (p < MAX_FLAG) flagged[p] = mb + r;
        }
      }
  }
#undef STAGE_B
}

// ---------------- numpy-fp32-exact re-argmin, coalesced wT reads ----------------
__global__ __launch_bounds__(256) void vq_refine_np2(
    const float* __restrict__ x, const float* __restrict__ wT,
    const float* __restrict__ Cnp, const int* __restrict__ flagged,
    const int* __restrict__ flag_count, int* __restrict__ indices) {
  __shared__ float xs[RB][D_EMB];
  __shared__ float Ash[RB];
  const int t = threadIdx.x;
  const int wv = t >> 6;
  const int kl = t & 63;
  const int r0 = wv * 4;
  int nf = *flag_count; if (nf > MAX_FLAG) nf = MAX_FLAG;
  int nblk = (nf + RB - 1) / RB;
  for (int bb = blockIdx.x; bb < nblk; bb += gridDim.x) {
    int base = bb * RB;
    int nr = nf - base; if (nr > RB) nr = RB;
    __syncthreads();
    {
      int r = t >> 4, p = t & 15;
      int src = flagged[base + (r < nr ? r : 0)];
      const float4* xp = (const float4*)(x + (size_t)src * D_EMB);
      float4* dst = (float4*)&xs[r][0];
#pragma unroll
      for (int i = 0; i < 4; ++i) dst[p + 16 * i] = xp[p + 16 * i];
    }
    __syncthreads();
    if (t < RB) Ash[t] = np_sumsq_256(xs[t]);
    __syncthreads();

    float B[4][16];
#pragma unroll
    for (int r = 0; r < 4; ++r)
#pragma unroll
      for (int j = 0; j < 16; ++j) B[r][j] = 0.f;

#pragma unroll 2
    for (int d = 0; d < D_EMB; ++d) {
      const float* wrow = wT + (size_t)d * K_CB + kl;
      float wv16[16];
#pragma unroll
      for (int j = 0; j < 16; ++j) wv16[j] = wrow[j * 64];
      float xv[4];
#pragma unroll
      for (int r = 0; r < 4; ++r) xv[r] = xs[r0 + r][d];
#pragma unroll
      for (int r = 0; r < 4; ++r)
#pragma unroll
        for (int j = 0; j < 16; ++j)
          B[r][j] = __fmaf_rn(xv[r], wv16[j], B[r][j]);
    }

    float cnv[16];
#pragma unroll
    for (int j = 0; j < 16; ++j) cnv[j] = Cnp[j * 64 + kl];

#pragma unroll
    for (int r = 0; r < 4; ++r) {
      float A = Ash[r0 + r];
      float bd = 3.4e38f; int bik = 0x7fffffff;
#pragma unroll
      for (int j = 0; j < 16; ++j) {
        float dq = __fadd_rn(__fsub_rn(A, __fmul_rn(2.0f, B[r][j])), cnv[j]);
        if (dq < bd) { bd = dq; bik = j * 64 + kl; }
      }
#pragma unroll
      for (int off = 1; off < 32; off <<= 1) {
        float od = __shfl_xor(bd, off, 64);
        int   ok = __shfl_xor(bik, off, 64);
        if (od < bd || (od == bd && ok < bik)) { bd = od; bik = ok; }
      }
      {
        float od = __shfl_xor(bd, 32, 64);
        int   ok = __shfl_xor(bik, 32, 64);
        if (od < bd || (od == bd && ok < bik)) { bd = od; bik = ok; }
      }
      if (kl == 0 && r0 + r < nr) indices[flagged[base + r0 + r]] = bik;
    }
  }
}

// ---------------- counting-sort scatter replacement ----------------
__global__ __launch_bounds__(256) void vq_hist(const int* __restrict__ indices,
                                               int* __restrict__ counts, int M) {
  __shared__ int h[K_CB];
#pragma unroll
  for (int i = threadIdx.x; i < K_CB; i += 256) h[i] = 0;
  __syncthreads();
  int r0 = blockIdx.x * 512;
  for (int i = threadIdx.x; i < 512 && r0 + i < M; i += 256)
    atomicAdd(&h[indices[r0 + i]], 1);
  __syncthreads();
  for (int i = threadIdx.x; i < K_CB; i += 256) {
    int v = h[i];
    if (v) atomicAdd(&counts[i], v);
  }
}

__global__ __launch_bounds__(1024) void vq_scan(const int* __restrict__ counts,
                                                int* __restrict__ offsets,
                                                int* __restrict__ cursor) {
  __shared__ int s[K_CB];
  int t = threadIdx.x;
  int v = counts[t];
  s[t] = v;
  __syncthreads();
  for (int off = 1; off < K_CB; off <<= 1) {
    int add = (t >= off) ? s[t - off] : 0;
    __syncthreads();
    s[t] += add;
    __syncthreads();
  }
  int excl = s[t] - v;
  offsets[t] = excl;
  cursor[t] = excl;
}

__global__ __launch_bounds__(256) void vq_pos(const int* __restrict__ indices,
                                              int* __restrict__ cursor,
                                              int* __restrict__ rows_sorted, int M) {
  int r = blockIdx.x * 256 + threadIdx.x;
  if (r < M) {
    int k = indices[r];
    int p = atomicAdd(&cursor[k], 1);
    rows_sorted[p] = r;
  }
}

__global__ __launch_bounds__(256) void vq_segsum(
    const float* __restrict__ x, const float* __restrict__ w,
    const int* __restrict__ offsets, const int* __restrict__ counts,
    const int* __restrict__ rows_sorted, float* __restrict__ q_out,
    float* __restrict__ emb_sum, float* __restrict__ loss_part) {
  __shared__ float4 red[256];
  __shared__ float lred[4];
  const int k = blockIdx.x;
  const int t = threadIdx.x;
  const int wv = t >> 6, d4 = t & 63;
  const float4 wvv = *(const float4*)(w + (size_t)k * D_EMB + d4 * 4);
  const int beg = offsets[k], cnt = counts[k];
  float4 acc = {0.f, 0.f, 0.f, 0.f};
  float ls = 0.f;
  for (int i = wv; i < cnt; i += 4) {
    int row = rows_sorted[beg + i];
    const float* xp = x + (size_t)row * D_EMB + d4 * 4;
    float4 xv = *(const float4*)xp;
    float4 qs;
    qs.x = xv.x + (wvv.x - xv.x);
    qs.y = xv.y + (wvv.y - xv.y);
    qs.z = xv.z + (wvv.z - xv.z);
    qs.w = xv.w + (wvv.w - xv.w);
    *(float4*)(q_out + (size_t)row * D_EMB + d4 * 4) = qs;
    float dx = xv.x - wvv.x, dy = xv.y - wvv.y, dz = xv.z - wvv.z, dw = xv.w - wvv.w;
    ls += dx * dx + dy * dy + dz * dz + dw * dw;
    acc.x += xv.x; acc.y += xv.y; acc.z += xv.z; acc.w += xv.w;
  }
  red[t] = acc;
#pragma unroll
  for (int off = 32; off >= 1; off >>= 1) ls += __shfl_xor(ls, off, 64);
  if ((t & 63) == 0) lred[wv] = ls;
  __syncthreads();
  if (t < 64) {
    float4 a = red[t], b = red[t + 64], c = red[t + 128], d = red[t + 192];
    float4 s;
    s.x = (a.x + b.x) + (c.x + d.x);
    s.y = (a.y + b.y) + (c.y + d.y);
    s.z = (a.z + b.z) + (c.z + d.z);
    s.w = (a.w + b.w) + (c.w + d.w);
    *(float4*)(emb_sum + (size_t)k * D_EMB + t * 4) = s;
  }
  if (t == 0) loss_part[k] = (lred[0] + lred[1]) + (lred[2] + lred[3]);
}

// ---------------- cluster-size EMA, n, norm, loss ----------------
__global__ __launch_bounds__(1024) void vq_fin_cs(
    const float* __restrict__ ema_cs, const int* __restrict__ counts,
    const float* __restrict__ loss_part, int n_part, float inv_MD,
    float* __restrict__ out_ncs, float* __restrict__ out_loss,
    float* __restrict__ norm_inv) {
  __shared__ float sm[1024];
  __shared__ float sl[1024];
  int k = threadIdx.x;
  float ncs = ema_cs[k] * DECAY_F + (float)counts[k] * OMD_F;
  out_ncs[k] = ncs;
  float ls = 0.f;
  for (int i = k; i < n_part; i += 1024) ls += loss_part[i];
  sm[k] = ncs; sl[k] = ls;
  __syncthreads();
  for (int s2 = 512; s2 > 0; s2 >>= 1) {
    if (k < s2) { sm[k] += sm[k + s2]; sl[k] += sl[k + s2]; }
    __syncthreads();
  }
  float n = sm[0];
  norm_inv[k] = (n + (float)K_CB * EPS_VQ) / (ncs + EPS_VQ);
  if (k == 0) out_loss[0] = sl[0] * inv_MD;
}

// ---------------- embedding EMA + new weight ----------------
__global__ __launch_bounds__(256) void vq_fin_w(
    const float* __restrict__ ema_emb, const float* __restrict__ emb_sum,
    const float* __restrict__ norm_inv, float* __restrict__ out_w,
    float* __restrict__ out_emb) {
  int e = blockIdx.x * 256 + threadIdx.x;
  float4 ee = ((const float4*)ema_emb)[e];
  float4 es = ((const float4*)emb_sum)[e];
  float4 ne;
  ne.x = ee.x * DECAY_F + es.x * OMD_F;
  ne.y = ee.y * DECAY_F + es.y * OMD_F;
  ne.z = ee.z * DECAY_F + es.z * OMD_F;
  ne.w = ee.w * DECAY_F + es.w * OMD_F;
  ((float4*)out_emb)[e] = ne;
  float ni = norm_inv[e >> 6];
  float4 nw;
  nw.x = ne.x * ni; nw.y = ne.y * ni; nw.z = ne.z * ni; nw.w = ne.w * ni;
  ((float4*)out_w)[e] = nw;
}

extern "C" void kernel_launch(void* const* d_in, const int* in_sizes, int n_in,
                              void* d_out, int out_size, void* d_ws, size_t ws_size,
                              hipStream_t stream) {
  const float* x       = (const float*)d_in[0];
  const float* w       = (const float*)d_in[1];
  const float* ema_cs  = (const float*)d_in[2];
  const float* ema_emb = (const float*)d_in[3];
  const int M = in_sizes[0] / D_EMB;   // 131072

  float* out      = (float*)d_out;
  float* out_q    = out;
  float* out_loss = out + (size_t)M * D_EMB;
  float* out_w    = out_loss + 1;
  float* out_ncs  = out_w + (size_t)K_CB * D_EMB;
  float* out_emb  = out_ncs + K_CB;

  float* ws          = (float*)d_ws;
  float* Cnp         = ws;                                      // 1024
  float* norm_inv    = Cnp + K_CB;                              // 1024
  float* emb_sum     = norm_inv + K_CB;                         // K*D
  int*   indices     = (int*)(emb_sum + (size_t)K_CB * D_EMB);  // M
  float* loss_part   = (float*)(indices + M);                   // K_CB
  int*   flagged     = (int*)(loss_part + K_CB);                // MAX_FLAG
  int*   flag_count  = flagged + MAX_FLAG;                      // 1 (+3 pad)
  int*   counts_i    = flag_count + 4;                          // K_CB
  int*   offsets     = counts_i + K_CB;                         // K_CB
  int*   cursor      = offsets + K_CB;                          // K_CB
  int*   rows_sorted = cursor + K_CB;                           // M
  unsigned short* w2 = (unsigned short*)(rows_sorted + M);      // K*D bf16 (0.5MB)
  float* wT          = (float*)(w2 + (size_t)K_CB * D_EMB);     // K*K fp32 (4MB)

  unsigned short* x2 = (unsigned short*)out_q;  // bf16(hi) of x; rewritten by vq_segsum

  hipMemsetAsync(flag_count, 0, sizeof(int), stream);
  hipMemsetAsync(counts_i, 0, K_CB * sizeof(int), stream);

  vq_split_hi<<<M * 64 / 256, 256, 0, stream>>>(x, x2, M);
  vq_split_hi<<<K_CB * 64 / 256, 256, 0, stream>>>(w, w2, K_CB);
  vq_transpose<<<64, 256, 0, stream>>>(w, wT);
  vq_wsq_np<<<K_CB / 256, 256, 0, stream>>>(w, Cnp);
  vq_gemm<<<M / 128, 256, 0, stream>>>(x2, w2, Cnp, indices, flagged, flag_count);
  vq_refine_np2<<<512, 256, 0, stream>>>(x, wT, Cnp, flagged, flag_count, indices);
  vq_hist<<<(M + 511) / 512, 256, 0, stream>>>(indices, counts_i, M);
  vq_scan<<<1, 1024, 0, stream>>>(counts_i, offsets, cursor);
  vq_pos<<<(M + 255) / 256, 256, 0, stream>>>(indices, cursor, rows_sorted, M);
  vq_segsum<<<K_CB, 256, 0, stream>>>(x, w, offsets, counts_i, rows_sorted,
                                      out_q, emb_sum, loss_part);
  vq_fin_cs<<<1, 1024, 0, stream>>>(ema_cs, counts_i, loss_part, K_CB,
                                    1.0f / ((float)M * (float)D_EMB),
                                    out_ncs, out_loss, norm_inv);
  vq_fin_w<<<K_CB * D_EMB / 4 / 256, 256, 0, stream>>>(ema_emb, emb_sum, norm_inv,
                                                       out_w, out_emb);
}

// Round 16
// 405.173 us; speedup vs baseline: 1.1084x; 1.1084x over previous
//
#include <hip/hip_runtime.h>

#define K_CB 1024
#define D_EMB 256
#define DECAY_F 0.900009f
#define OMD_F 0.099991f
#define EPS_VQ 1e-5f
#define MAX_FLAG 65536
#define GAP_TAU 3e-4f
#define RB 32                    // flagged rows per refine block (512 threads)

typedef __bf16 bf16x8 __attribute__((ext_vector_type(8)));
typedef float f32x4 __attribute__((ext_vector_type(4)));

__device__ __forceinline__ unsigned short bf16rn(float f) {
  unsigned u = __float_as_uint(f);
  return (unsigned short)((u + 0x7fffu + ((u >> 16) & 1u)) >> 16);
}

#define STAGE16(srcp, dstp)                                                        \
  __builtin_amdgcn_global_load_lds(                                               \
      (const __attribute__((address_space(1))) unsigned int*)(srcp),              \
      (__attribute__((address_space(3))) unsigned int*)(dstp), 16, 0, 0)

// ---------------- fp32 -> bf16 (hi only), x and w in one launch ----------------
__global__ __launch_bounds__(256) void vq_split_both(
    const float* __restrict__ x, unsigned short* __restrict__ x2,
    const float* __restrict__ w, unsigned short* __restrict__ w2, int M) {
  int g = blockIdx.x * 256 + threadIdx.x;
  int row = g >> 6, d0 = (g & 63) << 2;
  const float* src; unsigned short* dst; int r;
  if (row < M) { src = x; dst = x2; r = row; }
  else if (row < M + K_CB) { src = w; dst = w2; r = row - M; }
  else return;
  float4 v = *(const float4*)(src + (size_t)r * D_EMB + d0);
  ushort4 hi;
  hi.x = bf16rn(v.x); hi.y = bf16rn(v.y); hi.z = bf16rn(v.z); hi.w = bf16rn(v.w);
  *(ushort4*)(dst + (size_t)r * D_EMB + d0) = hi;
}

// ===== numpy float32 pairwise sum-of-squares emulation (exact) =====
__device__ __forceinline__ float np_block128_sq(const float* p) {
  float r[8];
#pragma unroll
  for (int j = 0; j < 8; ++j) r[j] = __fmul_rn(p[j], p[j]);
  for (int i = 8; i < 128; i += 8) {
#pragma unroll
    for (int j = 0; j < 8; ++j)
      r[j] = __fadd_rn(r[j], __fmul_rn(p[i + j], p[i + j]));
  }
  return __fadd_rn(__fadd_rn(__fadd_rn(r[0], r[1]), __fadd_rn(r[2], r[3])),
                   __fadd_rn(__fadd_rn(r[4], r[5]), __fadd_rn(r[6], r[7])));
}
__device__ __forceinline__ float np_sumsq_256(const float* p) {
  return __fadd_rn(np_block128_sq(p), np_block128_sq(p + 128));
}

// ---------------- fused: w transpose (blocks 0..63) + ||w||^2 numpy-exact (64..67) ----------------
__global__ __launch_bounds__(256) void vq_prep_w(const float* __restrict__ w,
                                                 float* __restrict__ wT,
                                                 float* __restrict__ Cnp) {
  if (blockIdx.x >= 64) {
    int k = (blockIdx.x - 64) * 256 + threadIdx.x;
    if (k < K_CB) Cnp[k] = np_sumsq_256(w + (size_t)k * D_EMB);
    return;
  }
  __shared__ float tile[64][65];
  int bk = (blockIdx.x & 15) * 64;
  int bd = (blockIdx.x >> 4) * 64;
  for (int i = threadIdx.x; i < 64 * 16; i += 256) {
    int kk = i >> 4, dd4 = (i & 15) * 4;
    float4 v = *(const float4*)(w + (size_t)(bk + kk) * D_EMB + bd + dd4);
    tile[kk][dd4]     = v.x; tile[kk][dd4 + 1] = v.y;
    tile[kk][dd4 + 2] = v.z; tile[kk][dd4 + 3] = v.w;
  }
  __syncthreads();
  for (int i = threadIdx.x; i < 64 * 64; i += 256) {
    int dd = i >> 6, kk = i & 63;
    wT[(size_t)(bd + dd) * K_CB + bk + kk] = tile[kk][dd];
  }
}

// ---------------- MFMA screening GEMM (r14 structure: single-buffer, 3 blocks/CU) ----------------
__global__ __launch_bounds__(256) void vq_gemm(
    const unsigned short* __restrict__ x2, const unsigned short* __restrict__ w2,
    const float* __restrict__ Cnp, int* __restrict__ indices,
    int* __restrict__ flagged, int* __restrict__ flag_count) {
  __shared__ unsigned short tA[128 * 64];
  __shared__ unsigned short tB[128 * 64];
  const int t = threadIdx.x;
  const int wid = t >> 6;
  const int wr = wid >> 1, wc = wid & 1;     // 2x2 wave grid, each 64(rows)x64(cols)
  const int lane = t & 63;
  const int q = lane >> 4, c = lane & 15;
  const int h = c & 7;
  const int mb = blockIdx.x * 128;

  const int srow = t >> 3;                   // 0..31
  const int ssl  = (t & 7) ^ (srow & 7);     // pre-swizzled 16B slot
  const unsigned short* aS[4];
  const unsigned short* bS[4];
#pragma unroll
  for (int cix = 0; cix < 4; ++cix) {
    int r = srow + 32 * cix;
    aS[cix] = x2 + (size_t)(mb + r) * D_EMB + ssl * 8;
    bS[cix] = w2 + (size_t)r * D_EMB + ssl * 8;
  }

#define STAGE_AB(koff)                                                        \
  do {                                                                        \
    _Pragma("unroll")                                                         \
    for (int cix = 0; cix < 4; ++cix) {                                       \
      STAGE16(aS[cix] + (koff) * 64, &tA[(cix * 256 + t) * 8]);               \
      STAGE16(bS[cix] + (koff) * 64, &tB[(cix * 256 + t) * 8]);               \
    }                                                                         \
  } while (0)

  float b1[4][4], b2v[4][4];
  int   bi[4][4];
#pragma unroll
  for (int m = 0; m < 4; ++m)
#pragma unroll
    for (int j = 0; j < 4; ++j) { b1[m][j] = 3.4e38f; b2v[m][j] = 3.4e38f; bi[m][j] = 0; }

  for (int nt = 0; nt < 8; ++nt) {
    const int nbase = nt << 7;
    f32x4 acc[4][4];
#pragma unroll
    for (int m = 0; m < 4; ++m)
#pragma unroll
      for (int n = 0; n < 4; ++n) acc[m][n] = (f32x4){0.f, 0.f, 0.f, 0.f};

    float cn[4]; int ck[4];
#pragma unroll
    for (int n = 0; n < 4; ++n) { ck[n] = nbase + wc * 64 + n * 16 + c; cn[n] = Cnp[ck[n]]; }

#pragma unroll
    for (int kc = 0; kc < 4; ++kc) {
      __syncthreads();                       // WAR: all waves done reading tile
      STAGE_AB(kc);
      __syncthreads();                       // vmcnt(0)+barrier: tile visible
      const unsigned short* tAc = tA;
      const unsigned short* tBc = tB;
      bf16x8 af0[4], af1[4];
#pragma unroll
      for (int m = 0; m < 4; ++m) {
        int r = (wr * 64 + m * 16 + c) * 64;
        af0[m] = *(const bf16x8*)&tAc[r + ((q) ^ h) * 8];
        af1[m] = *(const bf16x8*)&tAc[r + ((4 + q) ^ h) * 8];
      }
#pragma unroll
      for (int n = 0; n < 4; ++n) {
        int rb = (wc * 64 + n * 16 + c) * 64;
        bf16x8 bf0 = *(const bf16x8*)&tBc[rb + ((q) ^ h) * 8];
        bf16x8 bf1 = *(const bf16x8*)&tBc[rb + ((4 + q) ^ h) * 8];
#pragma unroll
        for (int m = 0; m < 4; ++m) {
          acc[m][n] = __builtin_amdgcn_mfma_f32_16x16x32_bf16(af0[m], bf0, acc[m][n], 0, 0, 0);
          acc[m][n] = __builtin_amdgcn_mfma_f32_16x16x32_bf16(af1[m], bf1, acc[m][n], 0, 0, 0);
        }
      }
    }

#pragma unroll
    for (int n = 0; n < 4; ++n)
#pragma unroll
      for (int m = 0; m < 4; ++m)
#pragma unroll
        for (int j = 0; j < 4; ++j) {
          float d = __fmaf_rn(-2.0f, acc[m][n][j], cn[n]);
          if (d < b1[m][j]) { b2v[m][j] = b1[m][j]; b1[m][j] = d; bi[m][j] = ck[n]; }
          else if (d < b2v[m][j]) b2v[m][j] = d;
        }

#pragma unroll
    for (int cix = 0; cix < 4; ++cix) bS[cix] += 128 * D_EMB;
  }

#pragma unroll
  for (int m = 0; m < 4; ++m)
#pragma unroll
    for (int j = 0; j < 4; ++j) {
      float db = b1[m][j], db2 = b2v[m][j];
      int   di = bi[m][j];
#pragma unroll
      for (int off = 1; off < 16; off <<= 1) {
        float ob  = __shfl_xor(db, off, 64);
        float ob2 = __shfl_xor(db2, off, 64);
        int   oi  = __shfl_xor(di, off, 64);
        float lo = fminf(db, ob), hi2 = fmaxf(db, ob);
        db2 = fminf(fminf(db2, ob2), hi2);
        di  = (ob < db || (ob == db && oi < di)) ? oi : di;
        db  = lo;
      }
      b1[m][j] = db; b2v[m][j] = db2; bi[m][j] = di;
    }

  // ---- cross-wave merge: each row is covered by waves (wr,0) and (wr,1) ----
  float* sB1 = (float*)tA;
  float* sB2 = sB1 + 128;
  int*   sBI = (int*)(sB2 + 128);
  __syncthreads();
  if (wc == 1 && c == 0) {
#pragma unroll
    for (int m = 0; m < 4; ++m)
#pragma unroll
      for (int j = 0; j < 4; ++j) {
        int r = wr * 64 + m * 16 + q * 4 + j;
        sB1[r] = b1[m][j]; sB2[r] = b2v[m][j]; sBI[r] = bi[m][j];
      }
  }
  __syncthreads();
  if (wc == 0 && c == 0) {
#pragma unroll
    for (int m = 0; m < 4; ++m)
#pragma unroll
      for (int j = 0; j < 4; ++j) {
        int r = wr * 64 + m * 16 + q * 4 + j;
        float o1 = sB1[r], o2 = sB2[r];
        int   oi = sBI[r];
        float best, sec; int bidx;
        if (o1 < b1[m][j] || (o1 == b1[m][j] && oi < bi[m][j])) {
          best = o1; bidx = oi; sec = fminf(o2, b1[m][j]);
        } else {
          best = b1[m][j]; bidx = bi[m][j]; sec = fminf(b2v[m][j], o1);
        }
        indices[mb + r] = bidx;
        if (sec - best < GAP_TAU) {
          int p = atomicAdd(flag_count, 1);
          if (p < MAX_FLAG) flagged[p] = mb + r;
        }
      }
  }
#undef STAGE_AB
}

// ---------------- numpy-fp32-exact re-argmin, coalesced wT reads (RB=32, 512 thr) ----------------
__global__ __launch_bounds__(512) void vq_refine_np2(
    const float* __restrict__ x, const float* __restrict__ wT,
    const float* __restrict__ Cnp, const int* __restrict__ flagged,
    const int* __restrict__ flag_count, int* __restrict__ indices) {
  __shared__ float xs[RB][D_EMB];
  __shared__ float Ash[RB];
  const int t = threadIdx.x;
  const int wv = t >> 6;                     // 0..7 waves
  const int kl = t & 63;
  const int r0 = wv * 4;                     // 4 rows per wave
  int nf = *flag_count; if (nf > MAX_FLAG) nf = MAX_FLAG;
  int nblk = (nf + RB - 1) / RB;
  for (int bb = blockIdx.x; bb < nblk; bb += gridDim.x) {
    int base = bb * RB;
    int nr = nf - base; if (nr > RB) nr = RB;
    __syncthreads();
    {
      int r = t >> 4, p = t & 15;            // 32 rows x 16 float4 slots
      int src = flagged[base + (r < nr ? r : 0)];
      const float4* xp = (const float4*)(x + (size_t)src * D_EMB);
      float4* dst = (float4*)&xs[r][0];
#pragma unroll
      for (int i = 0; i < 4; ++i) dst[p + 16 * i] = xp[p + 16 * i];
    }
    __syncthreads();
    if (t < RB) Ash[t] = np_sumsq_256(xs[t]);
    __syncthreads();

    float B[4][16];
#pragma unroll
    for (int r = 0; r < 4; ++r)
#pragma unroll
      for (int j = 0; j < 16; ++j) B[r][j] = 0.f;

#pragma unroll 2
    for (int d = 0; d < D_EMB; ++d) {
      const float* wrow = wT + (size_t)d * K_CB + kl;
      float wv16[16];
#pragma unroll
      for (int j = 0; j < 16; ++j) wv16[j] = wrow[j * 64];
      float xv[4];
#pragma unroll
      for (int r = 0; r < 4; ++r) xv[r] = xs[r0 + r][d];
#pragma unroll
      for (int r = 0; r < 4; ++r)
#pragma unroll
        for (int j = 0; j < 16; ++j)
          B[r][j] = __fmaf_rn(xv[r], wv16[j], B[r][j]);
    }

    float cnv[16];
#pragma unroll
    for (int j = 0; j < 16; ++j) cnv[j] = Cnp[j * 64 + kl];

#pragma unroll
    for (int r = 0; r < 4; ++r) {
      float A = Ash[r0 + r];
      float bd = 3.4e38f; int bik = 0x7fffffff;
#pragma unroll
      for (int j = 0; j < 16; ++j) {
        float dq = __fadd_rn(__fsub_rn(A, __fmul_rn(2.0f, B[r][j])), cnv[j]);
        if (dq < bd) { bd = dq; bik = j * 64 + kl; }
      }
#pragma unroll
      for (int off = 1; off < 64; off <<= 1) {
        float od = __shfl_xor(bd, off, 64);
        int   ok = __shfl_xor(bik, off, 64);
        if (od < bd || (od == bd && ok < bik)) { bd = od; bik = ok; }
      }
      if (kl == 0 && r0 + r < nr) indices[flagged[base + r0 + r]] = bik;
    }
  }
}

// ---------------- counting-sort scatter replacement ----------------
__global__ __launch_bounds__(256) void vq_hist(const int* __restrict__ indices,
                                               int* __restrict__ counts, int M) {
  __shared__ int h[K_CB];
#pragma unroll
  for (int i = threadIdx.x; i < K_CB; i += 256) h[i] = 0;
  __syncthreads();
  int r0 = blockIdx.x * 512;
  for (int i = threadIdx.x; i < 512 && r0 + i < M; i += 256)
    atomicAdd(&h[indices[r0 + i]], 1);
  __syncthreads();
  for (int i = threadIdx.x; i < K_CB; i += 256) {
    int v = h[i];
    if (v) atomicAdd(&counts[i], v);
  }
}

__global__ __launch_bounds__(1024) void vq_scan(const int* __restrict__ counts,
                                                int* __restrict__ offsets,
                                                int* __restrict__ cursor) {
  __shared__ int s[K_CB];
  int t = threadIdx.x;
  int v = counts[t];
  s[t] = v;
  __syncthreads();
  for (int off = 1; off < K_CB; off <<= 1) {
    int add = (t >= off) ? s[t - off] : 0;
    __syncthreads();
    s[t] += add;
    __syncthreads();
  }
  int excl = s[t] - v;
  offsets[t] = excl;
  cursor[t] = excl;
}

__global__ __launch_bounds__(256) void vq_pos(const int* __restrict__ indices,
                                              int* __restrict__ cursor,
                                              int* __restrict__ rows_sorted, int M) {
  int r = blockIdx.x * 256 + threadIdx.x;
  if (r < M) {
    int k = indices[r];
    int p = atomicAdd(&cursor[k], 1);
    rows_sorted[p] = r;
  }
}

__global__ __launch_bounds__(256) void vq_segsum(
    const float* __restrict__ x, const float* __restrict__ w,
    const int* __restrict__ offsets, const int* __restrict__ counts,
    const int* __restrict__ rows_sorted, float* __restrict__ q_out,
    float* __restrict__ emb_sum, float* __restrict__ loss_part) {
  __shared__ float4 red[256];
  __shared__ float lred[4];
  const int k = blockIdx.x;
  const int t = threadIdx.x;
  const int wv = t >> 6, d4 = t & 63;
  const float4 wvv = *(const float4*)(w + (size_t)k * D_EMB + d4 * 4);
  const int beg = offsets[k], cnt = counts[k];
  float4 acc = {0.f, 0.f, 0.f, 0.f};
  float ls = 0.f;
  for (int i = wv; i < cnt; i += 4) {
    int row = rows_sorted[beg + i];
    const float* xp = x + (size_t)row * D_EMB + d4 * 4;
    float4 xv = *(const float4*)xp;
    float4 qs;
    qs.x = xv.x + (wvv.x - xv.x);
    qs.y = xv.y + (wvv.y - xv.y);
    qs.z = xv.z + (wvv.z - xv.z);
    qs.w = xv.w + (wvv.w - xv.w);
    *(float4*)(q_out + (size_t)row * D_EMB + d4 * 4) = qs;
    float dx = xv.x - wvv.x, dy = xv.y - wvv.y, dz = xv.z - wvv.z, dw = xv.w - wvv.w;
    ls += dx * dx + dy * dy + dz * dz + dw * dw;
    acc.x += xv.x; acc.y += xv.y; acc.z += xv.z; acc.w += xv.w;
  }
  red[t] = acc;
#pragma unroll
  for (int off = 32; off >= 1; off >>= 1) ls += __shfl_xor(ls, off, 64);
  if ((t & 63) == 0) lred[wv] = ls;
  __syncthreads();
  if (t < 64) {
    float4 a = red[t], b = red[t + 64], c = red[t + 128], d = red[t + 192];
    float4 s;
    s.x = (a.x + b.x) + (c.x + d.x);
    s.y = (a.y + b.y) + (c.y + d.y);
    s.z = (a.z + b.z) + (c.z + d.z);
    s.w = (a.w + b.w) + (c.w + d.w);
    *(float4*)(emb_sum + (size_t)k * D_EMB + t * 4) = s;
  }
  if (t == 0) loss_part[k] = (lred[0] + lred[1]) + (lred[2] + lred[3]);
}

// ---------------- cluster-size EMA, n, norm, loss ----------------
__global__ __launch_bounds__(1024) void vq_fin_cs(
    const float* __restrict__ ema_cs, const int* __restrict__ counts,
    const float* __restrict__ loss_part, int n_part, float inv_MD,
    float* __restrict__ out_ncs, float* __restrict__ out_loss,
    float* __restrict__ norm_inv) {
  __shared__ float sm[1024];
  __shared__ float sl[1024];
  int k = threadIdx.x;
  float ncs = ema_cs[k] * DECAY_F + (float)counts[k] * OMD_F;
  out_ncs[k] = ncs;
  float ls = 0.f;
  for (int i = k; i < n_part; i += 1024) ls += loss_part[i];
  sm[k] = ncs; sl[k] = ls;
  __syncthreads();
  for (int s2 = 512; s2 > 0; s2 >>= 1) {
    if (k < s2) { sm[k] += sm[k + s2]; sl[k] += sl[k + s2]; }
    __syncthreads();
  }
  float n = sm[0];
  norm_inv[k] = (n + (float)K_CB * EPS_VQ) / (ncs + EPS_VQ);
  if (k == 0) out_loss[0] = sl[0] * inv_MD;
}

// ---------------- embedding EMA + new weight ----------------
__global__ __launch_bounds__(256) void vq_fin_w(
    const float* __restrict__ ema_emb, const float* __restrict__ emb_sum,
    const float* __restrict__ norm_inv, float* __restrict__ out_w,
    float* __restrict__ out_emb) {
  int e = blockIdx.x * 256 + threadIdx.x;
  float4 ee = ((const float4*)ema_emb)[e];
  float4 es = ((const float4*)emb_sum)[e];
  float4 ne;
  ne.x = ee.x * DECAY_F + es.x * OMD_F;
  ne.y = ee.y * DECAY_F + es.y * OMD_F;
  ne.z = ee.z * DECAY_F + es.z * OMD_F;
  ne.w = ee.w * DECAY_F + es.w * OMD_F;
  ((float4*)out_emb)[e] = ne;
  float ni = norm_inv[e >> 6];
  float4 nw;
  nw.x = ne.x * ni; nw.y = ne.y * ni; nw.z = ne.z * ni; nw.w = ne.w * ni;
  ((float4*)out_w)[e] = nw;
}

extern "C" void kernel_launch(void* const* d_in, const int* in_sizes, int n_in,
                              void* d_out, int out_size, void* d_ws, size_t ws_size,
                              hipStream_t stream) {
  const float* x       = (const float*)d_in[0];
  const float* w       = (const float*)d_in[1];
  const float* ema_cs  = (const float*)d_in[2];
  const float* ema_emb = (const float*)d_in[3];
  const int M = in_sizes[0] / D_EMB;   // 131072

  float* out      = (float*)d_out;
  float* out_q    = out;
  float* out_loss = out + (size_t)M * D_EMB;
  float* out_w    = out_loss + 1;
  float* out_ncs  = out_w + (size_t)K_CB * D_EMB;
  float* out_emb  = out_ncs + K_CB;

  float* ws          = (float*)d_ws;
  float* Cnp         = ws;                                      // 1024
  float* norm_inv    = Cnp + K_CB;                              // 1024
  float* emb_sum     = norm_inv + K_CB;                         // K*D
  int*   indices     = (int*)(emb_sum + (size_t)K_CB * D_EMB);  // M
  float* loss_part   = (float*)(indices + M);                   // K_CB
  int*   flagged     = (int*)(loss_part + K_CB);                // MAX_FLAG
  int*   flag_count  = flagged + MAX_FLAG;                      // 1 (+3 pad)
  int*   counts_i    = flag_count + 4;                          // K_CB
  int*   offsets     = counts_i + K_CB;                         // K_CB
  int*   cursor      = offsets + K_CB;                          // K_CB
  int*   rows_sorted = cursor + K_CB;                           // M
  unsigned short* w2 = (unsigned short*)(rows_sorted + M);      // K*D bf16 (0.5MB)
  float* wT          = (float*)(w2 + (size_t)K_CB * D_EMB);     // K*K fp32 (4MB)

  unsigned short* x2 = (unsigned short*)out_q;  // bf16(hi) of x; rewritten by vq_segsum

  hipMemsetAsync(flag_count, 0, sizeof(int), stream);
  hipMemsetAsync(counts_i, 0, K_CB * sizeof(int), stream);

  vq_split_both<<<(M + K_CB) / 4, 256, 0, stream>>>(x, x2, w, w2, M);
  vq_prep_w<<<68, 256, 0, stream>>>(w, wT, Cnp);
  vq_gemm<<<M / 128, 256, 0, stream>>>(x2, w2, Cnp, indices, flagged, flag_count);
  vq_refine_np2<<<512, 512, 0, stream>>>(x, wT, Cnp, flagged, flag_count, indices);
  vq_hist<<<(M + 511) / 512, 256, 0, stream>>>(indices, counts_i, M);
  vq_scan<<<1, 1024, 0, stream>>>(counts_i, offsets, cursor);
  vq_pos<<<(M + 255) / 256, 256, 0, stream>>>(indices, cursor, rows_sorted, M);
  vq_segsum<<<K_CB, 256, 0, stream>>>(x, w, offsets, counts_i, rows_sorted,
                                      out_q, emb_sum, loss_part);
  vq_fin_cs<<<1, 1024, 0, stream>>>(ema_cs, counts_i, loss_part, K_CB,
                                    1.0f / ((float)M * (float)D_EMB),
                                    out_ncs, out_loss, norm_inv);
  vq_fin_w<<<K_CB * D_EMB / 4 / 256, 256, 0, stream>>>(ema_emb, emb_sum, norm_inv,
                                                       out_w, out_emb);
}